// Round 6
// baseline (277.565 us; speedup 1.0000x reference)
//
#include <hip/hip_runtime.h>
#include <hip/hip_bf16.h>

#define NNODES   524288
#define NGRAPHS  4096
#define TPB      8     // 64-node tiles per block (1 wave); grid = NNODES/(64*TPB) = 1024
#define GS       12    // head LDS row stride (floats)

typedef __attribute__((ext_vector_type(8)))  short short8;
typedef __attribute__((ext_vector_type(4)))  float f32x4;
typedef __attribute__((ext_vector_type(16))) float f32x16;

static __device__ __forceinline__ unsigned short f2bf(float f) {
    __hip_bfloat16 h = __float2bfloat16(f);
    return *reinterpret_cast<unsigned short*>(&h);
}

// swizzled LDS offset (shorts): node-row 128 shorts, 16B chunks XOR-permuted
static __device__ __forceinline__ int swz(int node, int chunk) {
    return node * 128 + ((chunk ^ (node & 15)) << 3);
}

// ---- one-time: bf16 weight transposes. wT[of][k] = w[k][of]; w0p[of][16]:
// k<4 = w0, k==4 = b0 (bias folded into MFMA via B[k=4]=1.0), else 0 ----
__global__ __launch_bounds__(256) void prep_weights(
        const float* __restrict__ w0, const float* __restrict__ b0,
        const float* __restrict__ w1, const float* __restrict__ w2,
        unsigned short* __restrict__ w0p, unsigned short* __restrict__ w1T,
        unsigned short* __restrict__ w2T) {
    int e = blockIdx.x * 256 + threadIdx.x;
    if (e < 16384) {
        int k = e >> 7, n = e & 127;
        w1T[n * 128 + k] = f2bf(w1[e]);
    } else if (e < 32768) {
        int i = e - 16384;
        int k = i >> 7, n = i & 127;
        w2T[n * 128 + k] = f2bf(w2[i]);
    } else if (e < 34816) {
        int i = e - 32768;                 // w0p[128][16]
        int of = i >> 4, k = i & 15;
        unsigned short v = 0;
        if (k < 4)       v = f2bf(w0[k * 128 + of]);
        else if (k == 4) v = f2bf(b0[of]);
        w0p[i] = v;
    }
}

// ---- fused phi MLP: 1 wave/block, register-resident weights, 8 tiles/wave ----
__global__ __launch_bounds__(64, 1) void phi_kernel(
        const float* __restrict__ x, const int* __restrict__ batch,
        const unsigned short* __restrict__ w0p,
        const unsigned short* __restrict__ w1T, const float* __restrict__ b1,
        const unsigned short* __restrict__ w2T, const float* __restrict__ b2,
        float* __restrict__ g) {
    __shared__ __align__(16) unsigned short hb[64 * 128];   // 16 KB, wave-private
    const int lane = threadIdx.x;
    const int l31  = lane & 31;
    const int h    = lane >> 5;

    // ---- register-resident weights (loaded once per 512 nodes) ----
    short8 w0r[4];
    #pragma unroll
    for (int mt = 0; mt < 4; ++mt)
        w0r[mt] = *reinterpret_cast<const short8*>(w0p + (mt*32 + l31) * 16 + h*8);
    short8 w1r[4][8], w2r[4][8];
    #pragma unroll
    for (int mt = 0; mt < 4; ++mt)
        #pragma unroll
        for (int ks = 0; ks < 8; ++ks) {
            w1r[mt][ks] = *reinterpret_cast<const short8*>(
                w1T + (mt*32 + l31) * 128 + ks*16 + h*8);
            w2r[mt][ks] = *reinterpret_cast<const short8*>(
                w2T + (mt*32 + l31) * 128 + ks*16 + h*8);
        }
    float b2v[4];
    #pragma unroll
    for (int ntc = 0; ntc < 4; ++ntc) b2v[ntc] = b2[ntc*32 + l31];

    f32x16 acc[8];

    // swapped-C writeback: col=node (l31), row=of ((reg&3)+8*(reg>>2)+4*h)
    auto writeback = [&](const float* __restrict__ bias) {
        #pragma unroll
        for (int mt = 0; mt < 4; ++mt) {
            #pragma unroll
            for (int g4 = 0; g4 < 4; ++g4) {
                float4 bv = make_float4(0.f, 0.f, 0.f, 0.f);
                if (bias)
                    bv = *reinterpret_cast<const float4*>(bias + mt*32 + 8*g4 + 4*h);
                #pragma unroll
                for (int nt = 0; nt < 2; ++nt) {
                    const int node = nt*32 + l31;
                    const f32x16 A = acc[mt*2 + nt];
                    ushort4 s;
                    s.x = f2bf(fmaxf(A[g4*4+0] + bv.x, 0.f));
                    s.y = f2bf(fmaxf(A[g4*4+1] + bv.y, 0.f));
                    s.z = f2bf(fmaxf(A[g4*4+2] + bv.z, 0.f));
                    s.w = f2bf(fmaxf(A[g4*4+3] + bv.w, 0.f));
                    *reinterpret_cast<ushort4*>(&hb[swz(node, mt*4 + g4) + h*4]) = s;
                }
            }
        }
    };

    const int tile0 = blockIdx.x * TPB;

    // prefetch tile 0 inputs
    float4 xv0 = *reinterpret_cast<const float4*>(x + (size_t)(tile0*64 + l31) * 4);
    float4 xv1 = *reinterpret_cast<const float4*>(x + (size_t)(tile0*64 + 32 + l31) * 4);
    int    gi  = batch[tile0*64 + lane];

    #pragma unroll 1
    for (int t = 0; t < TPB; ++t) {
        const int n0 = (tile0 + t) * 64;

        // run-start mask for this tile
        const int gp = __shfl_up(gi, 1);
        const unsigned long long mask = __ballot((lane == 0) || (gi != gp));

        // ---- layer 1 (swapped: A = w0r, B = x rows; bias via B[k=4]=1) ----
        {
            short8 bf[2];
            const float4 xcur[2] = {xv0, xv1};
            #pragma unroll
            for (int nt = 0; nt < 2; ++nt) {
                short8 v = (short8){0,0,0,0,0,0,0,0};
                if (h == 0) {
                    v[0] = (short)f2bf(xcur[nt].x); v[1] = (short)f2bf(xcur[nt].y);
                    v[2] = (short)f2bf(xcur[nt].z); v[3] = (short)f2bf(xcur[nt].w);
                    v[4] = (short)0x3F80;   // bf16 1.0 -> adds b0 row of w0p
                }
                bf[nt] = v;
            }
            #pragma unroll
            for (int i = 0; i < 8; ++i) acc[i] = (f32x16){};
            #pragma unroll
            for (int mt = 0; mt < 4; ++mt)
                #pragma unroll
                for (int nt = 0; nt < 2; ++nt)
                    acc[mt*2 + nt] = __builtin_amdgcn_mfma_f32_32x32x16_bf16(
                        w0r[mt], bf[nt], acc[mt*2 + nt], 0, 0, 0);
        }

        // prefetch next tile's inputs (latency hidden behind layers 1-3)
        float4 nxv0 = xv0, nxv1 = xv1; int ngi = gi;
        if (t + 1 < TPB) {
            const int nn0 = n0 + 64;
            nxv0 = *reinterpret_cast<const float4*>(x + (size_t)(nn0 + l31) * 4);
            nxv1 = *reinterpret_cast<const float4*>(x + (size_t)(nn0 + 32 + l31) * 4);
            ngi  = batch[nn0 + lane];
        }

        writeback(nullptr);   // b0 already folded in

        // ---- layer 2 (swapped: A = w1r, B = hb node rows) ----
        #pragma unroll
        for (int i = 0; i < 8; ++i) acc[i] = (f32x16){};
        #pragma unroll
        for (int ks = 0; ks < 8; ++ks) {
            short8 b[2];
            #pragma unroll
            for (int nt = 0; nt < 2; ++nt)
                b[nt] = *reinterpret_cast<const short8*>(&hb[swz(nt*32 + l31, ks*2 + h)]);
            #pragma unroll
            for (int mt = 0; mt < 4; ++mt)
                #pragma unroll
                for (int nt = 0; nt < 2; ++nt)
                    acc[mt*2 + nt] = __builtin_amdgcn_mfma_f32_32x32x16_bf16(
                        w1r[mt][ks], b[nt], acc[mt*2 + nt], 0, 0, 0);
        }
        writeback(b1);   // in-place safe: all reads precede writes (in-order DS)

        // ---- layer 3 (normal: A = hb node rows, B = w2r) ----
        #pragma unroll
        for (int i = 0; i < 8; ++i) acc[i] = (f32x16){};
        #pragma unroll
        for (int ks = 0; ks < 8; ++ks) {
            short8 a[2];
            #pragma unroll
            for (int mtn = 0; mtn < 2; ++mtn)
                a[mtn] = *reinterpret_cast<const short8*>(&hb[swz(mtn*32 + l31, ks*2 + h)]);
            #pragma unroll
            for (int mtn = 0; mtn < 2; ++mtn)
                #pragma unroll
                for (int ntc = 0; ntc < 4; ++ntc)
                    acc[mtn*4 + ntc] = __builtin_amdgcn_mfma_f32_32x32x16_bf16(
                        a[mtn], w2r[ntc][ks], acc[mtn*4 + ntc], 0, 0, 0);
        }

        // ---- epilogue: register segmented sum. C: col=of (l31), row=node ----
        unsigned long long rem = mask & (mask - 1);
        int s = 0;
        while (true) {
            const int e = rem ? (int)__builtin_ctzll(rem) : 64;
            const int grun = __shfl(gi, s);
            const float cnt = (float)(e - s);
            float* gdst = g + (size_t)grun * 128;
            #pragma unroll
            for (int ntc = 0; ntc < 4; ++ntc) {
                float val = 0.f;
                #pragma unroll
                for (int mtn = 0; mtn < 2; ++mtn) {
                    const f32x16 A = acc[mtn*4 + ntc];
                    #pragma unroll
                    for (int r = 0; r < 16; ++r) {
                        const int node = mtn*32 + (r & 3) + 8*(r >> 2) + 4*h;
                        const float inc = (node >= s && node < e) ? 1.f : 0.f;
                        val = fmaf(A[r], inc, val);
                    }
                }
                val += __shfl_xor(val, 32);
                if (h == 0)
                    atomicAdd(gdst + ntc*32 + l31, fmaf(cnt, b2v[ntc], val));
            }
            if (!rem) break;
            s = e;
            rem &= rem - 1;
        }

        xv0 = nxv0; xv1 = nxv1; gi = ngi;
    }
}

// ---- F head: fused 3 layers, 8 graphs/block, 512 blocks ----
__global__ __launch_bounds__(256) void head_kernel(
        const float* __restrict__ g,
        const float* __restrict__ fw0, const float* __restrict__ fb0,
        const float* __restrict__ fw1, const float* __restrict__ fb1,
        const float* __restrict__ fw2, const float* __restrict__ fb2,
        float* __restrict__ out) {
    __shared__ float gS[128 * GS];
    __shared__ float h1T[256 * GS];
    __shared__ float red[4][16];
    const int tid = threadIdx.x;
    const int g0  = blockIdx.x * 8;

    {
        const int gr = tid >> 5, k0 = (tid & 31) * 4;
        const float4 v = *reinterpret_cast<const float4*>(
            g + (size_t)(g0 + gr) * 128 + k0);
        gS[(k0+0)*GS + gr] = v.x; gS[(k0+1)*GS + gr] = v.y;
        gS[(k0+2)*GS + gr] = v.z; gS[(k0+3)*GS + gr] = v.w;
    }
    __syncthreads();

    float a1[8];
    #pragma unroll
    for (int i = 0; i < 8; ++i) a1[i] = 0.f;
    #pragma unroll 4
    for (int k = 0; k < 128; ++k) {
        const float w = fw0[k * 256 + tid];
        const f32x4 v0 = *reinterpret_cast<const f32x4*>(&gS[k*GS]);
        const f32x4 v1 = *reinterpret_cast<const f32x4*>(&gS[k*GS + 4]);
        #pragma unroll
        for (int j = 0; j < 4; ++j) {
            a1[j]     = fmaf(v0[j], w, a1[j]);
            a1[4 + j] = fmaf(v1[j], w, a1[4 + j]);
        }
    }
    {
        const float bb = fb0[tid];
        f32x4 s0, s1;
        #pragma unroll
        for (int j = 0; j < 4; ++j) {
            s0[j] = fmaxf(a1[j] + bb, 0.f);
            s1[j] = fmaxf(a1[4 + j] + bb, 0.f);
        }
        *reinterpret_cast<f32x4*>(&h1T[tid*GS])     = s0;
        *reinterpret_cast<f32x4*>(&h1T[tid*GS + 4]) = s1;
    }
    __syncthreads();

    float a2[8];
    #pragma unroll
    for (int i = 0; i < 8; ++i) a2[i] = 0.f;
    #pragma unroll 4
    for (int k = 0; k < 256; ++k) {
        const float w = fw1[k * 256 + tid];
        const f32x4 v0 = *reinterpret_cast<const f32x4*>(&h1T[k*GS]);
        const f32x4 v1 = *reinterpret_cast<const f32x4*>(&h1T[k*GS + 4]);
        #pragma unroll
        for (int j = 0; j < 4; ++j) {
            a2[j]     = fmaf(v0[j], w, a2[j]);
            a2[4 + j] = fmaf(v1[j], w, a2[4 + j]);
        }
    }

    float p[16];
    {
        const float bb  = fb1[tid];
        const float w2a = fw2[tid*2 + 0];
        const float w2b = fw2[tid*2 + 1];
        #pragma unroll
        for (int i = 0; i < 8; ++i) {
            const float h2 = fmaxf(a2[i] + bb, 0.f);
            p[i*2 + 0] = h2 * w2a;
            p[i*2 + 1] = h2 * w2b;
        }
    }
    #pragma unroll
    for (int i = 0; i < 16; ++i) {
        float v = p[i];
        v += __shfl_xor(v, 32); v += __shfl_xor(v, 16); v += __shfl_xor(v, 8);
        v += __shfl_xor(v, 4);  v += __shfl_xor(v, 2);  v += __shfl_xor(v, 1);
        p[i] = v;
    }
    if ((tid & 63) == 0) {
        #pragma unroll
        for (int i = 0; i < 16; ++i) red[tid >> 6][i] = p[i];
    }
    __syncthreads();
    if (tid < 16)
        out[g0*2 + tid] = red[0][tid] + red[1][tid] + red[2][tid] + red[3][tid]
                        + fb2[tid & 1];
}

extern "C" void kernel_launch(void* const* d_in, const int* in_sizes, int n_in,
                              void* d_out, int out_size, void* d_ws, size_t ws_size,
                              hipStream_t stream) {
    const float* x   = (const float*)d_in[0];
    // d_in[1] edge_index: mathematically dead (update() ignores aggr_out) — never read
    const int*   batch = (const int*)d_in[2];
    const float* w0  = (const float*)d_in[3];
    const float* b0  = (const float*)d_in[4];
    const float* w1  = (const float*)d_in[5];
    const float* b1  = (const float*)d_in[6];
    const float* w2  = (const float*)d_in[7];
    const float* b2  = (const float*)d_in[8];
    const float* fw0 = (const float*)d_in[9];
    const float* fb0 = (const float*)d_in[10];
    const float* fw1 = (const float*)d_in[11];
    const float* fb1 = (const float*)d_in[12];
    const float* fw2 = (const float*)d_in[13];
    const float* fb2 = (const float*)d_in[14];
    float* out = (float*)d_out;

    float* g = (float*)d_ws;                                        // 2 MB
    unsigned short* w1T = (unsigned short*)((char*)d_ws + (size_t)NGRAPHS * 128 * 4);
    unsigned short* w2T = w1T + 128 * 128;
    unsigned short* w0p = w2T + 128 * 128;                          // 4 KB

    (void)hipMemsetAsync(g, 0, (size_t)NGRAPHS * 128 * sizeof(float), stream);
    prep_weights<<<136, 256, 0, stream>>>(w0, b0, w1, w2, w0p, w1T, w2T);
    phi_kernel<<<NNODES / (64 * TPB), 64, 0, stream>>>(
        x, batch, w0p, w1T, b1, w2T, b2, g);
    head_kernel<<<NGRAPHS / 8, 256, 0, stream>>>(g, fw0, fb0, fw1, fb1, fw2, fb2, out);
}